// Round 9
// baseline (713.668 us; speedup 1.0000x reference)
//
#include <hip/hip_runtime.h>
#include <math.h>

#define BATCH 65536
#define HID   128

using bf16x8 = __attribute__((ext_vector_type(8))) short;
using f32x4  = __attribute__((ext_vector_type(4))) float;

// ---- ws layout (short-element offsets) ----
#define E1H 0                 // eW1^T hi [128 p][32 k] (global-read path for L1)
#define E1L 4096
#define SWB 8192              // 6 pre-swizzled LDS-image blobs, 32768 shorts each:
                              // 0=E2, 1=A1emb, 2=A1mean, 3=A2, 4=V1, 5=V2
#define BIASF 204800          // 7 x 128 f32 (perm: eb1,eb2,vb1,vb2,ab1,ab2,aW3)
#define MEANH 206592          // mean hi [BATCH][128] bf16 (frag-slot order)
#define MEANL (MEANH + BATCH*HID)
#define WS_ELEMS_FULL (MEANL + BATCH*HID)

__device__ __forceinline__ float4 ld4(const float* p) { return *reinterpret_cast<const float4*>(p); }

__device__ __forceinline__ unsigned cvtpk(float a, float b) {
    unsigned r;
    asm("v_cvt_pk_bf16_f32 %0, %1, %2" : "=v"(r) : "v"(a), "v"(b));
    return r;
}

// tanh = 1 - 2/(2^(2*log2e*x)+1); inf-safe both ends
__device__ __forceinline__ float tanh_f(float x) {
    float t = __builtin_amdgcn_exp2f(x * 2.8853900817779268f);
    float r = __builtin_amdgcn_rcpf(t + 1.f);
    return 1.f - 2.f * r;
}

__device__ __forceinline__ f32x4 mfma16(bf16x8 a, bf16x8 b, f32x4 c) {
    return __builtin_amdgcn_mfma_f32_16x16x32_bf16(a, b, c, 0, 0, 0);
}

__device__ __forceinline__ bf16x8 pk8(unsigned u0, unsigned u1, unsigned u2, unsigned u3) {
    union { unsigned u[4]; bf16x8 v; } x;
    x.u[0] = u0; x.u[1] = u1; x.u[2] = u2; x.u[3] = u3;
    return x.v;
}

__device__ __forceinline__ void split_pack(float v0, float v1, float v2, float v3,
        unsigned& uh0, unsigned& uh1, unsigned& ul0, unsigned& ul1) {
    uh0 = cvtpk(v0, v1); uh1 = cvtpk(v2, v3);
    float f0 = __uint_as_float(uh0 << 16), f1 = __uint_as_float(uh0 & 0xffff0000u);
    float f2 = __uint_as_float(uh1 << 16), f3 = __uint_as_float(uh1 & 0xffff0000u);
    ul0 = cvtpk(v0 - f0, v1 - f1); ul1 = cvtpk(v2 - f2, v3 - f3);
}

__device__ __forceinline__ void zacc(f32x4 acc[2][8]) {
    #pragma unroll
    for (int rt = 0; rt < 2; ++rt)
        #pragma unroll
        for (int t = 0; t < 8; ++t) acc[rt][t] = f32x4{0.f, 0.f, 0.f, 0.f};
}

// channel permutation: phys p -> logical channel
__device__ __forceinline__ int permc(int p) {
    return 32 * ((p >> 4) & 3) + 8 * ((p >> 2) & 3) + 4 * (p >> 6) + (p & 3);
}

// ---- async global -> LDS (16B/lane), linear dest; src blob is pre-swizzled ----
__device__ __forceinline__ void gload16(const void* g, void* l) {
    __builtin_amdgcn_global_load_lds(
        (const __attribute__((address_space(1))) void*)g,
        (__attribute__((address_space(3))) void*)l, 16, 0, 0);
}
// stage one 64KB blob: wave w covers bytes [w*8K, (w+1)*8K)
__device__ __forceinline__ void stage64k(short* dst, const short* __restrict__ src,
                                         int w, int lane) {
    const char* g = (const char*)src + w * 8192 + lane * 16;
    char* l = (char*)dst + w * 8192;
    #pragma unroll
    for (int s = 0; s < 8; ++s) gload16(g + s * 1024, l + s * 1024);
}

// ---- hidden layer from LDS W: acc[rt][t] += W^T[16t+lm][32ks+8q+j] * X[rt][k] ----
__device__ __forceinline__ void mm_lds(f32x4 acc[2][8],
        const bf16x8 Bh[2][4], const bf16x8 Bl[2][4],
        const short* Wlds, int sE, int sO)
{
    #pragma unroll
    for (int tp = 0; tp < 4; ++tp) {
        #pragma unroll
        for (int ks = 0; ks < 4; ++ks) {
            const int base = ((ks & 1) ? sO : sE) + (ks >> 1) * 64 + tp * 4096;
            bf16x8 wh0 = *(const bf16x8*)(Wlds + base);
            bf16x8 wh1 = *(const bf16x8*)(Wlds + base + 2048);
            bf16x8 wl0 = *(const bf16x8*)(Wlds + base + 16384);
            bf16x8 wl1 = *(const bf16x8*)(Wlds + base + 16384 + 2048);
            __builtin_amdgcn_s_setprio(1);
            acc[0][2*tp  ] = mfma16(wh0, Bh[0][ks], acc[0][2*tp  ]);
            acc[0][2*tp+1] = mfma16(wh1, Bh[0][ks], acc[0][2*tp+1]);
            acc[1][2*tp  ] = mfma16(wh0, Bh[1][ks], acc[1][2*tp  ]);
            acc[1][2*tp+1] = mfma16(wh1, Bh[1][ks], acc[1][2*tp+1]);
            acc[0][2*tp  ] = mfma16(wh0, Bl[0][ks], acc[0][2*tp  ]);
            acc[0][2*tp+1] = mfma16(wh1, Bl[0][ks], acc[0][2*tp+1]);
            acc[1][2*tp  ] = mfma16(wh0, Bl[1][ks], acc[1][2*tp  ]);
            acc[1][2*tp+1] = mfma16(wh1, Bl[1][ks], acc[1][2*tp+1]);
            acc[0][2*tp  ] = mfma16(wl0, Bh[0][ks], acc[0][2*tp  ]);
            acc[0][2*tp+1] = mfma16(wl1, Bh[0][ks], acc[0][2*tp+1]);
            acc[1][2*tp  ] = mfma16(wl0, Bh[1][ks], acc[1][2*tp  ]);
            acc[1][2*tp+1] = mfma16(wl1, Bh[1][ks], acc[1][2*tp+1]);
            __builtin_amdgcn_s_setprio(0);
        }
    }
}

// ---- L1 (K=32) with W streamed from global (tiny: 16KB) ----
__device__ __forceinline__ void mm_l1(f32x4 acc[2][8],
        const bf16x8 X0h[2], const bf16x8 X0l[2],
        const short* __restrict__ Wh, const short* __restrict__ Wl, int wb)
{
    #pragma unroll
    for (int tp = 0; tp < 4; ++tp) {
        const short* whp = Wh + wb + tp * 1024;
        const short* wlp = Wl + wb + tp * 1024;
        bf16x8 wh0 = *(const bf16x8*)(whp);
        bf16x8 wh1 = *(const bf16x8*)(whp + 512);
        bf16x8 wl0 = *(const bf16x8*)(wlp);
        bf16x8 wl1 = *(const bf16x8*)(wlp + 512);
        __builtin_amdgcn_s_setprio(1);
        acc[0][2*tp  ] = mfma16(wh0, X0h[0], acc[0][2*tp  ]);
        acc[0][2*tp+1] = mfma16(wh1, X0h[0], acc[0][2*tp+1]);
        acc[1][2*tp  ] = mfma16(wh0, X0h[1], acc[1][2*tp  ]);
        acc[1][2*tp+1] = mfma16(wh1, X0h[1], acc[1][2*tp+1]);
        acc[0][2*tp  ] = mfma16(wh0, X0l[0], acc[0][2*tp  ]);
        acc[0][2*tp+1] = mfma16(wh1, X0l[0], acc[0][2*tp+1]);
        acc[1][2*tp  ] = mfma16(wh0, X0l[1], acc[1][2*tp  ]);
        acc[1][2*tp+1] = mfma16(wh1, X0l[1], acc[1][2*tp+1]);
        acc[0][2*tp  ] = mfma16(wl0, X0h[0], acc[0][2*tp  ]);
        acc[0][2*tp+1] = mfma16(wl1, X0h[0], acc[0][2*tp+1]);
        acc[1][2*tp  ] = mfma16(wl0, X0h[1], acc[1][2*tp  ]);
        acc[1][2*tp+1] = mfma16(wl1, X0h[1], acc[1][2*tp+1]);
        __builtin_amdgcn_s_setprio(0);
    }
}

// ---- epilogue: acc -> tanh(+bias) -> new hi/lo state (B-frag-ready) ----
__device__ __forceinline__ void epi_state(const f32x4 acc[2][8], const float* __restrict__ bp,
        int q4, bf16x8 Nh[2][4], bf16x8 Nl[2][4])
{
    #pragma unroll
    for (int ks = 0; ks < 4; ++ks) {
        float4 b0 = ld4(bp + 16 * ks + q4);
        float4 b1 = ld4(bp + 16 * ks + 64 + q4);
        #pragma unroll
        for (int rt = 0; rt < 2; ++rt) {
            unsigned h0, h1, h2, h3, l0, l1, l2, l3;
            split_pack(tanh_f(acc[rt][ks][0] + b0.x), tanh_f(acc[rt][ks][1] + b0.y),
                       tanh_f(acc[rt][ks][2] + b0.z), tanh_f(acc[rt][ks][3] + b0.w),
                       h0, h1, l0, l1);
            split_pack(tanh_f(acc[rt][ks+4][0] + b1.x), tanh_f(acc[rt][ks+4][1] + b1.y),
                       tanh_f(acc[rt][ks+4][2] + b1.z), tanh_f(acc[rt][ks+4][3] + b1.w),
                       h2, h3, l2, l3);
            Nh[rt][ks] = pk8(h0, h1, h2, h3);
            Nl[rt][ks] = pk8(l0, l1, l2, l3);
        }
    }
}

// ---- X0 B-frags direct from global (k = 8q+j; q=3 -> zeros) ----
__device__ __forceinline__ void build_x0(bf16x8 X0h[2], bf16x8 X0l[2],
        const float* __restrict__ self_obs, const float* __restrict__ obs,
        int r0w, int lm, int q)
{
    #pragma unroll
    for (int rt = 0; rt < 2; ++rt) {
        int row = r0w + 16 * rt + lm;
        const float* sp = self_obs + (size_t)(row & (BATCH - 1)) * 18;
        float x0 = 0.f, x1 = 0.f, x2 = 0.f, x3 = 0.f, x4 = 0.f, x5 = 0.f, x6 = 0.f, x7 = 0.f;
        if (q == 0) {
            x0 = sp[0]; x1 = sp[1]; x2 = sp[2]; x3 = sp[3];
            x4 = sp[4]; x5 = sp[5]; x6 = sp[6]; x7 = sp[7];
        } else if (q == 1) {
            x0 = sp[8]; x1 = sp[9]; x2 = sp[10]; x3 = sp[11];
            x4 = sp[12]; x5 = sp[13]; x6 = sp[14]; x7 = sp[15];
        } else if (q == 2) {
            x0 = sp[16]; x1 = sp[17];
            const float* op = obs + (size_t)(row >> 3) * 66 + 18 + (row & 7) * 6;
            x2 = op[0]; x3 = op[1]; x4 = op[2]; x5 = op[3]; x6 = op[4]; x7 = op[5];
        }
        unsigned h0, h1, h2, h3, l0, l1, l2, l3;
        split_pack(x0, x1, x2, x3, h0, h1, l0, l1);
        split_pack(x4, x5, x6, x7, h2, h3, l2, l3);
        X0h[rt] = pk8(h0, h1, h2, h3);
        X0l[rt] = pk8(l0, l1, l2, l3);
    }
}

// XCD-aware bijection on 2048 blocks: sharing set {v+256j} lands at hw = c+8j+64m (same XCD)
__device__ __forceinline__ int remap(int hw) {
    return (((hw >> 3) & 7) << 8) | ((hw & 7) << 5) | (hw >> 6);
}

// ================= prep: blobs (pre-swizzled LDS images) + biases =================
__global__ void prep_w(const float* __restrict__ eW1, const float* __restrict__ eW2,
                       const float* __restrict__ vW1, const float* __restrict__ vW2,
                       const float* __restrict__ aW1, const float* __restrict__ aW2,
                       const float* __restrict__ eb1, const float* __restrict__ eb2,
                       const float* __restrict__ vb1, const float* __restrict__ vb2,
                       const float* __restrict__ ab1, const float* __restrict__ ab2,
                       const float* __restrict__ aW3,
                       short* __restrict__ ws)
{
    int t = blockIdx.x * blockDim.x + threadIdx.x;
    if (t >= 103296) return;
    if (t >= 102400) {               // permuted biases + w3 (f32)
        int i = t - 102400, arr = i >> 7, p = i & 127;
        int c = permc(p);
        float v;
        if      (arr == 0) v = eb1[c];
        else if (arr == 1) v = eb2[c];
        else if (arr == 2) v = vb1[c];
        else if (arr == 3) v = vb2[c];
        else if (arr == 4) v = ab1[c];
        else if (arr == 5) v = ab2[c];
        else               v = aW3[c];
        ((float*)(ws + BIASF))[arr * 128 + p] = v;
        return;
    }
    float v; int dh, dl;
    if (t < 4096) {                  // E1: plain [p][32k] layout (L1 global path)
        int p = t >> 5, k = t & 31;
        v = (k < 24) ? eW1[k * HID + permc(p)] : 0.f;
        dh = E1H + t; dl = E1L + t;
    } else {                         // 6 staged blobs, LDS-image order with XOR swizzle
        int u = t - 4096;
        int blob = u >> 14, vv = u & 16383;
        int p = vv >> 7;
        int k = (vv & 127) ^ ((p & 7) << 3);
        int c = permc(p);
        if      (blob == 0) v = eW2[k * HID + c];
        else if (blob == 1) v = aW1[k * HID + c];
        else if (blob == 2) v = aW1[(128 + k) * HID + c];
        else if (blob == 3) v = aW2[k * HID + c];
        else if (blob == 4) v = vW1[k * HID + c];
        else                v = vW2[k * HID + c];
        dh = SWB + blob * 32768 + vv;
        dl = dh + 16384;
    }
    unsigned uu = __float_as_uint(v);
    unsigned h = (uu + 0x7fffu + ((uu >> 16) & 1u)) >> 16;
    float lf = v - __uint_as_float(h << 16);
    ws[dh] = (short)h;
    ws[dl] = (short)(__float_as_uint(lf) >> 16);
}

// ================= kernel A: L1,L2 -> group means =================
__global__ __launch_bounds__(512, 4)
void qk_mean(const float* __restrict__ self_obs, const float* __restrict__ obs,
             short* ws, int use_ml)
{
    __shared__ __align__(16) short Wb[32768];
    const int tid = threadIdx.x, lane = tid & 63, w = tid >> 6;
    const int lm = lane & 15, q = lane >> 4;
    const int r0w = remap(blockIdx.x) * 256 + w * 32;
    const float* bf = (const float*)(ws + BIASF);
    const int sE = (lm * 128 + 8 * q) ^ ((lm & 7) << 3);
    const int sO = (lm * 128 + 8 * q + 32) ^ ((lm & 7) << 3);

    stage64k(Wb, ws + SWB, w, lane);      // E2

    f32x4 acc[2][8];
    bf16x8 X0h[2], X0l[2];
    build_x0(X0h, X0l, self_obs, obs, r0w, lm, q);
    zacc(acc);
    mm_l1(acc, X0h, X0l, ws + E1H, ws + E1L, lm * 32 + q * 8);
    bf16x8 Hh[2][4], Hl[2][4];
    epi_state(acc, bf, q * 4, Hh, Hl);    // eb1
    __syncthreads();                      // E2 staged ready

    zacc(acc);
    mm_lds(acc, Hh, Hl, Wb, sE, sO);      // L2

    const float* b2 = bf + 128;           // eb2
    short* mh  = ws + MEANH;
    short* mlp = ws + MEANL;
    #pragma unroll
    for (int rt = 0; rt < 2; ++rt) {
        float m[8][4];
        #pragma unroll
        for (int ks = 0; ks < 4; ++ks) {
            float4 b0 = ld4(b2 + 16 * ks + 4 * q);
            float4 b1 = ld4(b2 + 16 * ks + 64 + 4 * q);
            m[ks][0] = tanh_f(acc[rt][ks][0] + b0.x);
            m[ks][1] = tanh_f(acc[rt][ks][1] + b0.y);
            m[ks][2] = tanh_f(acc[rt][ks][2] + b0.z);
            m[ks][3] = tanh_f(acc[rt][ks][3] + b0.w);
            m[ks+4][0] = tanh_f(acc[rt][ks+4][0] + b1.x);
            m[ks+4][1] = tanh_f(acc[rt][ks+4][1] + b1.y);
            m[ks+4][2] = tanh_f(acc[rt][ks+4][2] + b1.z);
            m[ks+4][3] = tanh_f(acc[rt][ks+4][3] + b1.w);
        }
        #pragma unroll
        for (int t = 0; t < 8; ++t)
            #pragma unroll
            for (int e = 0; e < 4; ++e) {
                float v = m[t][e];
                v += __shfl_xor(v, 1); v += __shfl_xor(v, 2); v += __shfl_xor(v, 4);
                m[t][e] = v * 0.125f;
            }
        if ((lm & 7) == 0) {
            int g = (r0w >> 3) + 2 * rt + (lm >> 3);
            #pragma unroll
            for (int ks = 0; ks < 4; ++ks) {
                unsigned h0, h1, h2, h3, l0, l1, l2, l3;
                split_pack(m[ks][0], m[ks][1], m[ks][2], m[ks][3], h0, h1, l0, l1);
                split_pack(m[ks+4][0], m[ks+4][1], m[ks+4][2], m[ks+4][3], h2, h3, l2, l3);
                *(bf16x8*)(mh + (size_t)g * 128 + 32 * ks + 8 * q) = pk8(h0, h1, h2, h3);
                if (use_ml)
                    *(bf16x8*)(mlp + (size_t)g * 128 + 32 * ks + 8 * q) = pk8(l0, l1, l2, l3);
            }
        }
    }
}

// ================= kernel B: full pipeline, single 64KB W buffer =================
__global__ __launch_bounds__(512, 4)
void qk_main(const float* __restrict__ self_obs, const float* __restrict__ obs,
             short* ws, float* __restrict__ out, int use_ml)
{
    __shared__ __align__(16) short Wb[32768];      // 64 KB -> 2 blocks/CU
    const int tid = threadIdx.x, lane = tid & 63, w = tid >> 6;
    const int lm = lane & 15, q = lane >> 4;
    const int r0w = remap(blockIdx.x) * 256 + w * 32;
    const float* bf = (const float*)(ws + BIASF);
    const int sE = (lm * 128 + 8 * q) ^ ((lm & 7) << 3);
    const int sO = (lm * 128 + 8 * q + 32) ^ ((lm & 7) << 3);

    f32x4 acc[2][8];

    // ---- P0: stage E2; L1 from global W (overlaps); epi->H
    stage64k(Wb, ws + SWB + 0 * 32768, w, lane);
    {
        bf16x8 X0h[2], X0l[2];
        build_x0(X0h, X0l, self_obs, obs, r0w, lm, q);
        zacc(acc);
        mm_l1(acc, X0h, X0l, ws + E1H, ws + E1L, lm * 32 + q * 8);
    }
    bf16x8 Hh[2][4], Hl[2][4];
    epi_state(acc, bf, q * 4, Hh, Hl);                     // eb1 -> H
    __syncthreads();                                       // E2 ready

    // ---- P1: L2; then stage A1emb + mean loads under the epi
    zacc(acc);
    mm_lds(acc, Hh, Hl, Wb, sE, sO);
    __syncthreads();                                       // done reading E2
    stage64k(Wb, ws + SWB + 1 * 32768, w, lane);
    bf16x8 Mh[2][4], Ml[2][4];
    {
        const short* mh  = ws + MEANH;
        const short* mlp = ws + MEANL;
        const size_t mr0 = (size_t)((r0w + lm) & (BATCH - 1)) * 128;
        const size_t mr1 = (size_t)((r0w + 16 + lm) & (BATCH - 1)) * 128;
        const bf16x8 z8 = {0, 0, 0, 0, 0, 0, 0, 0};
        #pragma unroll
        for (int ks = 0; ks < 4; ++ks) {
            Mh[0][ks] = *(const bf16x8*)(mh + mr0 + 32 * ks + 8 * q);
            Mh[1][ks] = *(const bf16x8*)(mh + mr1 + 32 * ks + 8 * q);
            if (use_ml) {
                Ml[0][ks] = *(const bf16x8*)(mlp + mr0 + 32 * ks + 8 * q);
                Ml[1][ks] = *(const bf16x8*)(mlp + mr1 + 32 * ks + 8 * q);
            } else { Ml[0][ks] = z8; Ml[1][ks] = z8; }
        }
    }
    bf16x8 Eh[2][4], El[2][4];
    epi_state(acc, bf + 128, q * 4, Eh, El);               // eb2 -> E (lives long)
    __syncthreads();                                       // A1emb ready

    // ---- P2: L5 emb half
    zacc(acc);
    mm_lds(acc, Eh, El, Wb, sE, sO);
    __syncthreads();                                       // done reading A1emb
    stage64k(Wb, ws + SWB + 2 * 32768, w, lane);
    __syncthreads();                                       // A1mean ready

    // ---- P3: L5 mean half (accumulate)
    mm_lds(acc, Mh, Ml, Wb, sE, sO);
    __syncthreads();                                       // done reading A1mean
    stage64k(Wb, ws + SWB + 3 * 32768, w, lane);
    bf16x8 Ah[2][4], Al[2][4];
    epi_state(acc, bf + 4 * 128, q * 4, Ah, Al);           // ab1 -> A
    __syncthreads();                                       // A2 ready

    // ---- P4: L6; scores + softmax in-register (overlaps V1 staging)
    zacc(acc);
    mm_lds(acc, Ah, Al, Wb, sE, sO);
    __syncthreads();                                       // done reading A2
    stage64k(Wb, ws + SWB + 4 * 32768, w, lane);
    float a0, a1;
    {
        const float* b6  = bf + 5 * 128;   // ab2
        const float* w3p = bf + 6 * 128;   // aW3 (ab3 cancels in softmax)
        float p0 = 0.f, p1 = 0.f;
        #pragma unroll
        for (int t = 0; t < 8; ++t) {
            float4 b  = ld4(b6 + 16 * t + 4 * q);
            float4 wv = ld4(w3p + 16 * t + 4 * q);
            p0 += tanh_f(acc[0][t][0] + b.x) * wv.x + tanh_f(acc[0][t][1] + b.y) * wv.y
                + tanh_f(acc[0][t][2] + b.z) * wv.z + tanh_f(acc[0][t][3] + b.w) * wv.w;
            p1 += tanh_f(acc[1][t][0] + b.x) * wv.x + tanh_f(acc[1][t][1] + b.y) * wv.y
                + tanh_f(acc[1][t][2] + b.z) * wv.z + tanh_f(acc[1][t][3] + b.w) * wv.w;
        }
        p0 += __shfl_xor(p0, 16); p0 += __shfl_xor(p0, 32);
        p1 += __shfl_xor(p1, 16); p1 += __shfl_xor(p1, 32);
        float m0 = p0, m1 = p1;
        m0 = fmaxf(m0, __shfl_xor(m0, 1)); m0 = fmaxf(m0, __shfl_xor(m0, 2)); m0 = fmaxf(m0, __shfl_xor(m0, 4));
        m1 = fmaxf(m1, __shfl_xor(m1, 1)); m1 = fmaxf(m1, __shfl_xor(m1, 2)); m1 = fmaxf(m1, __shfl_xor(m1, 4));
        float e0 = __expf(p0 - m0), e1 = __expf(p1 - m1);
        float s0 = e0, s1 = e1;
        s0 += __shfl_xor(s0, 1); s0 += __shfl_xor(s0, 2); s0 += __shfl_xor(s0, 4);
        s1 += __shfl_xor(s1, 1); s1 += __shfl_xor(s1, 2); s1 += __shfl_xor(s1, 4);
        a0 = e0 * __builtin_amdgcn_rcpf(s0);
        a1 = e1 * __builtin_amdgcn_rcpf(s1);
    }
    __syncthreads();                                       // V1 ready

    // ---- P5: L3
    zacc(acc);
    mm_lds(acc, Eh, El, Wb, sE, sO);
    __syncthreads();                                       // done reading V1
    stage64k(Wb, ws + SWB + 5 * 32768, w, lane);
    bf16x8 Vh[2][4], Vl[2][4];
    epi_state(acc, bf + 2 * 128, q * 4, Vh, Vl);           // vb1 -> V
    __syncthreads();                                       // V2 ready

    // ---- P6: L4; attn-weighted group sum -> out
    zacc(acc);
    mm_lds(acc, Vh, Vl, Wb, sE, sO);
    const float* b4 = bf + 3 * 128;                        // vb2
    #pragma unroll
    for (int rt = 0; rt < 2; ++rt) {
        const float av = rt ? a1 : a0;
        float o[8][4];
        #pragma unroll
        for (int ks = 0; ks < 4; ++ks) {
            float4 b0 = ld4(b4 + 16 * ks + 4 * q);
            float4 b1 = ld4(b4 + 16 * ks + 64 + 4 * q);
            o[ks][0] = av * tanh_f(acc[rt][ks][0] + b0.x);
            o[ks][1] = av * tanh_f(acc[rt][ks][1] + b0.y);
            o[ks][2] = av * tanh_f(acc[rt][ks][2] + b0.z);
            o[ks][3] = av * tanh_f(acc[rt][ks][3] + b0.w);
            o[ks+4][0] = av * tanh_f(acc[rt][ks+4][0] + b1.x);
            o[ks+4][1] = av * tanh_f(acc[rt][ks+4][1] + b1.y);
            o[ks+4][2] = av * tanh_f(acc[rt][ks+4][2] + b1.z);
            o[ks+4][3] = av * tanh_f(acc[rt][ks+4][3] + b1.w);
        }
        #pragma unroll
        for (int t = 0; t < 8; ++t)
            #pragma unroll
            for (int e = 0; e < 4; ++e) {
                float v = o[t][e];
                v += __shfl_xor(v, 1); v += __shfl_xor(v, 2); v += __shfl_xor(v, 4);
                o[t][e] = v;
            }
        if ((lm & 7) == 0) {
            int g = (r0w >> 3) + 2 * rt + (lm >> 3);
            #pragma unroll
            for (int ks = 0; ks < 4; ++ks) {
                *(float4*)(out + (size_t)g * 128 + 32 * ks + 8 * q) =
                    make_float4(o[ks][0], o[ks][1], o[ks][2], o[ks][3]);
                *(float4*)(out + (size_t)g * 128 + 32 * ks + 8 * q + 4) =
                    make_float4(o[ks+4][0], o[ks+4][1], o[ks+4][2], o[ks+4][3]);
            }
        }
    }
}

extern "C" void kernel_launch(void* const* d_in, const int* in_sizes, int n_in,
                              void* d_out, int out_size, void* d_ws, size_t ws_size,
                              hipStream_t stream) {
    const float* self_obs = (const float*)d_in[0];
    const float* obs      = (const float*)d_in[1];
    const float* eW1 = (const float*)d_in[2];  const float* eb1 = (const float*)d_in[3];
    const float* eW2 = (const float*)d_in[4];  const float* eb2 = (const float*)d_in[5];
    const float* vW1 = (const float*)d_in[6];  const float* vb1 = (const float*)d_in[7];
    const float* vW2 = (const float*)d_in[8];  const float* vb2 = (const float*)d_in[9];
    const float* aW1 = (const float*)d_in[10]; const float* ab1 = (const float*)d_in[11];
    const float* aW2 = (const float*)d_in[12]; const float* ab2 = (const float*)d_in[13];
    const float* aW3 = (const float*)d_in[14];
    float* out = (float*)d_out;
    short* ws = (short*)d_ws;

    int use_ml = (ws_size >= (size_t)WS_ELEMS_FULL * sizeof(short)) ? 1 : 0;

    prep_w<<<404, 256, 0, stream>>>(eW1, eW2, vW1, vW2, aW1, aW2,
                                    eb1, eb2, vb1, vb2, ab1, ab2, aW3, ws);

    dim3 grid(2048);   // 2048 blocks x 8 waves x 32 rows = 524288 rows
    qk_mean<<<grid, 512, 0, stream>>>(self_obs, obs, ws, use_ml);
    qk_main<<<grid, 512, 0, stream>>>(self_obs, obs, ws, out, use_ml);
}

// Round 10
// 385.862 us; speedup vs baseline: 1.8495x; 1.8495x over previous
//
#include <hip/hip_runtime.h>
#include <math.h>

#define BATCH 65536
#define HID   128
#define NTHREADS 256   // 4 waves x 32 rows = 128 rows/block

using bf16x8 = __attribute__((ext_vector_type(8))) short;
using f32x4  = __attribute__((ext_vector_type(4))) float;

// ---- ws layout (short-element offsets) ----
#define E1H 0                 // eW1^T hi [128 p][32 k] (global-read path for L1)
#define E1L 4096
#define SWB 8192              // 6 pre-swizzled LDS-image blobs, 32768 shorts each:
                              // 0=E2, 1=A1emb, 2=A1mean, 3=A2, 4=V1, 5=V2
#define BIASF 204800          // 7 x 128 f32 (perm: eb1,eb2,vb1,vb2,ab1,ab2,aW3)
#define MEANH 206592          // mean hi [BATCH][128] bf16 (frag-slot order)
#define WS_ELEMS_FULL (MEANH + BATCH*HID)

__device__ __forceinline__ float4 ld4(const float* p) { return *reinterpret_cast<const float4*>(p); }

__device__ __forceinline__ unsigned cvtpk(float a, float b) {
    unsigned r;
    asm("v_cvt_pk_bf16_f32 %0, %1, %2" : "=v"(r) : "v"(a), "v"(b));
    return r;
}

// tanh = 1 - 2/(2^(2*log2e*x)+1); inf-safe both ends
__device__ __forceinline__ float tanh_f(float x) {
    float t = __builtin_amdgcn_exp2f(x * 2.8853900817779268f);
    float r = __builtin_amdgcn_rcpf(t + 1.f);
    return 1.f - 2.f * r;
}

__device__ __forceinline__ f32x4 mfma16(bf16x8 a, bf16x8 b, f32x4 c) {
    return __builtin_amdgcn_mfma_f32_16x16x32_bf16(a, b, c, 0, 0, 0);
}

__device__ __forceinline__ bf16x8 pk8(unsigned u0, unsigned u1, unsigned u2, unsigned u3) {
    union { unsigned u[4]; bf16x8 v; } x;
    x.u[0] = u0; x.u[1] = u1; x.u[2] = u2; x.u[3] = u3;
    return x.v;
}

__device__ __forceinline__ void split_pack(float v0, float v1, float v2, float v3,
        unsigned& uh0, unsigned& uh1, unsigned& ul0, unsigned& ul1) {
    uh0 = cvtpk(v0, v1); uh1 = cvtpk(v2, v3);
    float f0 = __uint_as_float(uh0 << 16), f1 = __uint_as_float(uh0 & 0xffff0000u);
    float f2 = __uint_as_float(uh1 << 16), f3 = __uint_as_float(uh1 & 0xffff0000u);
    ul0 = cvtpk(v0 - f0, v1 - f1); ul1 = cvtpk(v2 - f2, v3 - f3);
}

__device__ __forceinline__ void zacc(f32x4 acc[2][8]) {
    #pragma unroll
    for (int rt = 0; rt < 2; ++rt)
        #pragma unroll
        for (int t = 0; t < 8; ++t) acc[rt][t] = f32x4{0.f, 0.f, 0.f, 0.f};
}

// channel permutation: phys p -> logical channel
__device__ __forceinline__ int permc(int p) {
    return 32 * ((p >> 4) & 3) + 8 * ((p >> 2) & 3) + 4 * (p >> 6) + (p & 3);
}

// ---- async global -> LDS (16B/lane), linear dest; src blob is pre-swizzled ----
__device__ __forceinline__ void gload16(const void* g, void* l) {
    __builtin_amdgcn_global_load_lds(
        (const __attribute__((address_space(1))) void*)g,
        (__attribute__((address_space(3))) void*)l, 16, 0, 0);
}
// stage one 64KB blob: wave w covers bytes [w*16K, (w+1)*16K)
__device__ __forceinline__ void stage64k(short* dst, const short* __restrict__ src,
                                         int w, int lane) {
    const char* g = (const char*)src + w * 16384 + lane * 16;
    char* l = (char*)dst + w * 16384;
    #pragma unroll
    for (int s = 0; s < 16; ++s) gload16(g + s * 1024, l + s * 1024);
}

// ---- hidden layer from LDS W (TERMS=3: Wh*Bh + Wl*Bh + Wh*Bl; TERMS=2: no Bl term) ----
template<int TERMS>
__device__ __forceinline__ void mm_lds(f32x4 acc[2][8],
        const bf16x8 Bh[2][4], const bf16x8 Bl[2][4],
        const short* Wlds, int sE, int sO)
{
    #pragma unroll
    for (int tp = 0; tp < 4; ++tp) {
        #pragma unroll
        for (int ks = 0; ks < 4; ++ks) {
            const int base = ((ks & 1) ? sO : sE) + (ks >> 1) * 64 + tp * 4096;
            bf16x8 wh0 = *(const bf16x8*)(Wlds + base);
            bf16x8 wh1 = *(const bf16x8*)(Wlds + base + 2048);
            bf16x8 wl0 = *(const bf16x8*)(Wlds + base + 16384);
            bf16x8 wl1 = *(const bf16x8*)(Wlds + base + 16384 + 2048);
            __builtin_amdgcn_s_setprio(1);
            acc[0][2*tp  ] = mfma16(wh0, Bh[0][ks], acc[0][2*tp  ]);
            acc[0][2*tp+1] = mfma16(wh1, Bh[0][ks], acc[0][2*tp+1]);
            acc[1][2*tp  ] = mfma16(wh0, Bh[1][ks], acc[1][2*tp  ]);
            acc[1][2*tp+1] = mfma16(wh1, Bh[1][ks], acc[1][2*tp+1]);
            acc[0][2*tp  ] = mfma16(wl0, Bh[0][ks], acc[0][2*tp  ]);
            acc[0][2*tp+1] = mfma16(wl1, Bh[0][ks], acc[0][2*tp+1]);
            acc[1][2*tp  ] = mfma16(wl0, Bh[1][ks], acc[1][2*tp  ]);
            acc[1][2*tp+1] = mfma16(wl1, Bh[1][ks], acc[1][2*tp+1]);
            if constexpr (TERMS == 3) {
                acc[0][2*tp  ] = mfma16(wh0, Bl[0][ks], acc[0][2*tp  ]);
                acc[0][2*tp+1] = mfma16(wh1, Bl[0][ks], acc[0][2*tp+1]);
                acc[1][2*tp  ] = mfma16(wh0, Bl[1][ks], acc[1][2*tp  ]);
                acc[1][2*tp+1] = mfma16(wh1, Bl[1][ks], acc[1][2*tp+1]);
            }
            __builtin_amdgcn_s_setprio(0);
        }
    }
}

// ---- L1 (K=32) with W streamed from global (tiny: 16KB, L2-hot) ----
__device__ __forceinline__ void mm_l1(f32x4 acc[2][8],
        const bf16x8 X0h[2], const bf16x8 X0l[2],
        const short* __restrict__ Wh, const short* __restrict__ Wl, int wb)
{
    #pragma unroll
    for (int tp = 0; tp < 4; ++tp) {
        const short* whp = Wh + wb + tp * 1024;
        const short* wlp = Wl + wb + tp * 1024;
        bf16x8 wh0 = *(const bf16x8*)(whp);
        bf16x8 wh1 = *(const bf16x8*)(whp + 512);
        bf16x8 wl0 = *(const bf16x8*)(wlp);
        bf16x8 wl1 = *(const bf16x8*)(wlp + 512);
        __builtin_amdgcn_s_setprio(1);
        acc[0][2*tp  ] = mfma16(wh0, X0h[0], acc[0][2*tp  ]);
        acc[0][2*tp+1] = mfma16(wh1, X0h[0], acc[0][2*tp+1]);
        acc[1][2*tp  ] = mfma16(wh0, X0h[1], acc[1][2*tp  ]);
        acc[1][2*tp+1] = mfma16(wh1, X0h[1], acc[1][2*tp+1]);
        acc[0][2*tp  ] = mfma16(wh0, X0l[0], acc[0][2*tp  ]);
        acc[0][2*tp+1] = mfma16(wh1, X0l[0], acc[0][2*tp+1]);
        acc[1][2*tp  ] = mfma16(wh0, X0l[1], acc[1][2*tp  ]);
        acc[1][2*tp+1] = mfma16(wh1, X0l[1], acc[1][2*tp+1]);
        acc[0][2*tp  ] = mfma16(wl0, X0h[0], acc[0][2*tp  ]);
        acc[0][2*tp+1] = mfma16(wl1, X0h[0], acc[0][2*tp+1]);
        acc[1][2*tp  ] = mfma16(wl0, X0h[1], acc[1][2*tp  ]);
        acc[1][2*tp+1] = mfma16(wl1, X0h[1], acc[1][2*tp+1]);
        __builtin_amdgcn_s_setprio(0);
    }
}

// ---- epilogue: acc -> tanh(+bias) -> hi/lo state (B-frag-ready) ----
__device__ __forceinline__ void epi_state(const f32x4 acc[2][8], const float* __restrict__ bp,
        int q4, bf16x8 Nh[2][4], bf16x8 Nl[2][4])
{
    #pragma unroll
    for (int ks = 0; ks < 4; ++ks) {
        float4 b0 = ld4(bp + 16 * ks + q4);
        float4 b1 = ld4(bp + 16 * ks + 64 + q4);
        #pragma unroll
        for (int rt = 0; rt < 2; ++rt) {
            unsigned h0, h1, h2, h3, l0, l1, l2, l3;
            split_pack(tanh_f(acc[rt][ks][0] + b0.x), tanh_f(acc[rt][ks][1] + b0.y),
                       tanh_f(acc[rt][ks][2] + b0.z), tanh_f(acc[rt][ks][3] + b0.w),
                       h0, h1, l0, l1);
            split_pack(tanh_f(acc[rt][ks+4][0] + b1.x), tanh_f(acc[rt][ks+4][1] + b1.y),
                       tanh_f(acc[rt][ks+4][2] + b1.z), tanh_f(acc[rt][ks+4][3] + b1.w),
                       h2, h3, l2, l3);
            Nh[rt][ks] = pk8(h0, h1, h2, h3);
            Nl[rt][ks] = pk8(l0, l1, l2, l3);
        }
    }
}

// ---- epilogue, hi-only (for attn-path states; no residual) ----
__device__ __forceinline__ void epi_state_hi(const f32x4 acc[2][8], const float* __restrict__ bp,
        int q4, bf16x8 Nh[2][4])
{
    #pragma unroll
    for (int ks = 0; ks < 4; ++ks) {
        float4 b0 = ld4(bp + 16 * ks + q4);
        float4 b1 = ld4(bp + 16 * ks + 64 + q4);
        #pragma unroll
        for (int rt = 0; rt < 2; ++rt) {
            unsigned h0 = cvtpk(tanh_f(acc[rt][ks][0] + b0.x), tanh_f(acc[rt][ks][1] + b0.y));
            unsigned h1 = cvtpk(tanh_f(acc[rt][ks][2] + b0.z), tanh_f(acc[rt][ks][3] + b0.w));
            unsigned h2 = cvtpk(tanh_f(acc[rt][ks+4][0] + b1.x), tanh_f(acc[rt][ks+4][1] + b1.y));
            unsigned h3 = cvtpk(tanh_f(acc[rt][ks+4][2] + b1.z), tanh_f(acc[rt][ks+4][3] + b1.w));
            Nh[rt][ks] = pk8(h0, h1, h2, h3);
        }
    }
}

// ---- X0 B-frags direct from global (k = 8q+j; q=3 -> zeros) ----
__device__ __forceinline__ void build_x0(bf16x8 X0h[2], bf16x8 X0l[2],
        const float* __restrict__ self_obs, const float* __restrict__ obs,
        int r0w, int lm, int q)
{
    #pragma unroll
    for (int rt = 0; rt < 2; ++rt) {
        int row = r0w + 16 * rt + lm;
        const float* sp = self_obs + (size_t)(row & (BATCH - 1)) * 18;
        float x0 = 0.f, x1 = 0.f, x2 = 0.f, x3 = 0.f, x4 = 0.f, x5 = 0.f, x6 = 0.f, x7 = 0.f;
        if (q == 0) {
            x0 = sp[0]; x1 = sp[1]; x2 = sp[2]; x3 = sp[3];
            x4 = sp[4]; x5 = sp[5]; x6 = sp[6]; x7 = sp[7];
        } else if (q == 1) {
            x0 = sp[8]; x1 = sp[9]; x2 = sp[10]; x3 = sp[11];
            x4 = sp[12]; x5 = sp[13]; x6 = sp[14]; x7 = sp[15];
        } else if (q == 2) {
            x0 = sp[16]; x1 = sp[17];
            const float* op = obs + (size_t)(row >> 3) * 66 + 18 + (row & 7) * 6;
            x2 = op[0]; x3 = op[1]; x4 = op[2]; x5 = op[3]; x6 = op[4]; x7 = op[5];
        }
        unsigned h0, h1, h2, h3, l0, l1, l2, l3;
        split_pack(x0, x1, x2, x3, h0, h1, l0, l1);
        split_pack(x4, x5, x6, x7, h2, h3, l2, l3);
        X0h[rt] = pk8(h0, h1, h2, h3);
        X0l[rt] = pk8(l0, l1, l2, l3);
    }
}

// XCD-aware bijection on 4096 blocks: sharing set {v+512j} lands on same XCD, adjacent slots
__device__ __forceinline__ int remap(int hw) {
    return (((hw >> 3) & 7) << 9) | ((hw & 7) << 6) | (hw >> 6);
}

// ================= prep: blobs (pre-swizzled LDS images) + biases =================
__global__ void prep_w(const float* __restrict__ eW1, const float* __restrict__ eW2,
                       const float* __restrict__ vW1, const float* __restrict__ vW2,
                       const float* __restrict__ aW1, const float* __restrict__ aW2,
                       const float* __restrict__ eb1, const float* __restrict__ eb2,
                       const float* __restrict__ vb1, const float* __restrict__ vb2,
                       const float* __restrict__ ab1, const float* __restrict__ ab2,
                       const float* __restrict__ aW3,
                       short* __restrict__ ws)
{
    int t = blockIdx.x * blockDim.x + threadIdx.x;
    if (t >= 103296) return;
    if (t >= 102400) {               // permuted biases + w3 (f32)
        int i = t - 102400, arr = i >> 7, p = i & 127;
        int c = permc(p);
        float v;
        if      (arr == 0) v = eb1[c];
        else if (arr == 1) v = eb2[c];
        else if (arr == 2) v = vb1[c];
        else if (arr == 3) v = vb2[c];
        else if (arr == 4) v = ab1[c];
        else if (arr == 5) v = ab2[c];
        else               v = aW3[c];
        ((float*)(ws + BIASF))[arr * 128 + p] = v;
        return;
    }
    float v; int dh, dl;
    if (t < 4096) {                  // E1: plain [p][32k] layout (L1 global path)
        int p = t >> 5, k = t & 31;
        v = (k < 24) ? eW1[k * HID + permc(p)] : 0.f;
        dh = E1H + t; dl = E1L + t;
    } else {                         // 6 staged blobs, LDS-image order with XOR swizzle
        int u = t - 4096;
        int blob = u >> 14, vv = u & 16383;
        int p = vv >> 7;
        int k = (vv & 127) ^ ((p & 7) << 3);
        int c = permc(p);
        if      (blob == 0) v = eW2[k * HID + c];
        else if (blob == 1) v = aW1[k * HID + c];
        else if (blob == 2) v = aW1[(128 + k) * HID + c];
        else if (blob == 3) v = aW2[k * HID + c];
        else if (blob == 4) v = vW1[k * HID + c];
        else                v = vW2[k * HID + c];
        dh = SWB + blob * 32768 + vv;
        dl = dh + 16384;
    }
    unsigned uu = __float_as_uint(v);
    unsigned h = (uu + 0x7fffu + ((uu >> 16) & 1u)) >> 16;
    float lf = v - __uint_as_float(h << 16);
    ws[dh] = (short)h;
    ws[dl] = (short)(__float_as_uint(lf) >> 16);
}

// ================= kernel A: L1,L2 -> group means (hi only) =================
__global__ __launch_bounds__(NTHREADS, 2)
void qk_mean(const float* __restrict__ self_obs, const float* __restrict__ obs,
             short* ws)
{
    __shared__ __align__(16) short Wb[32768];
    const int tid = threadIdx.x, lane = tid & 63, w = tid >> 6;
    const int lm = lane & 15, q = lane >> 4;
    const int r0w = remap(blockIdx.x) * 128 + w * 32;
    const float* bf = (const float*)(ws + BIASF);
    const int sE = (lm * 128 + 8 * q) ^ ((lm & 7) << 3);
    const int sO = (lm * 128 + 8 * q + 32) ^ ((lm & 7) << 3);

    stage64k(Wb, ws + SWB, w, lane);      // E2

    f32x4 acc[2][8];
    bf16x8 X0h[2], X0l[2];
    build_x0(X0h, X0l, self_obs, obs, r0w, lm, q);
    zacc(acc);
    mm_l1(acc, X0h, X0l, ws + E1H, ws + E1L, lm * 32 + q * 8);
    bf16x8 Hh[2][4], Hl[2][4];
    epi_state(acc, bf, q * 4, Hh, Hl);    // eb1
    __syncthreads();                      // E2 staged ready

    zacc(acc);
    mm_lds<3>(acc, Hh, Hl, Wb, sE, sO);   // L2

    const float* b2 = bf + 128;           // eb2
    short* mh = ws + MEANH;
    #pragma unroll
    for (int rt = 0; rt < 2; ++rt) {
        float m[8][4];
        #pragma unroll
        for (int ks = 0; ks < 4; ++ks) {
            float4 b0 = ld4(b2 + 16 * ks + 4 * q);
            float4 b1 = ld4(b2 + 16 * ks + 64 + 4 * q);
            m[ks][0] = tanh_f(acc[rt][ks][0] + b0.x);
            m[ks][1] = tanh_f(acc[rt][ks][1] + b0.y);
            m[ks][2] = tanh_f(acc[rt][ks][2] + b0.z);
            m[ks][3] = tanh_f(acc[rt][ks][3] + b0.w);
            m[ks+4][0] = tanh_f(acc[rt][ks+4][0] + b1.x);
            m[ks+4][1] = tanh_f(acc[rt][ks+4][1] + b1.y);
            m[ks+4][2] = tanh_f(acc[rt][ks+4][2] + b1.z);
            m[ks+4][3] = tanh_f(acc[rt][ks+4][3] + b1.w);
        }
        #pragma unroll
        for (int t = 0; t < 8; ++t)
            #pragma unroll
            for (int e = 0; e < 4; ++e) {
                float v = m[t][e];
                v += __shfl_xor(v, 1); v += __shfl_xor(v, 2); v += __shfl_xor(v, 4);
                m[t][e] = v * 0.125f;
            }
        if ((lm & 7) == 0) {
            int g = (r0w >> 3) + 2 * rt + (lm >> 3);
            #pragma unroll
            for (int ks = 0; ks < 4; ++ks) {
                unsigned h0 = cvtpk(m[ks][0], m[ks][1]);
                unsigned h1 = cvtpk(m[ks][2], m[ks][3]);
                unsigned h2 = cvtpk(m[ks+4][0], m[ks+4][1]);
                unsigned h3 = cvtpk(m[ks+4][2], m[ks+4][3]);
                *(bf16x8*)(mh + (size_t)g * 128 + 32 * ks + 8 * q) = pk8(h0, h1, h2, h3);
            }
        }
    }
}

// ================= kernel B: full pipeline, single 64KB W buffer =================
__global__ __launch_bounds__(NTHREADS, 2)
void qk_main(const float* __restrict__ self_obs, const float* __restrict__ obs,
             short* ws, float* __restrict__ out)
{
    __shared__ __align__(16) short Wb[32768];      // 64 KB -> 2 blocks/CU
    const int tid = threadIdx.x, lane = tid & 63, w = tid >> 6;
    const int lm = lane & 15, q = lane >> 4;
    const int r0w = remap(blockIdx.x) * 128 + w * 32;
    const float* bf = (const float*)(ws + BIASF);
    const int sE = (lm * 128 + 8 * q) ^ ((lm & 7) << 3);
    const int sO = (lm * 128 + 8 * q + 32) ^ ((lm & 7) << 3);

    f32x4 acc[2][8];
    float a0, a1;

    // ---- P0: stage E2; L1 from global W (overlaps); epi->H
    stage64k(Wb, ws + SWB + 0 * 32768, w, lane);
    {
        bf16x8 X0h[2], X0l[2];
        build_x0(X0h, X0l, self_obs, obs, r0w, lm, q);
        zacc(acc);
        mm_l1(acc, X0h, X0l, ws + E1H, ws + E1L, lm * 32 + q * 8);
    }
    bf16x8 Hh[2][4], Hl[2][4];
    epi_state(acc, bf, q * 4, Hh, Hl);                     // eb1 -> H
    __syncthreads();                                       // E2 ready

    // ---- P1: L2; then stage A1emb + mean(hi) loads under the epi
    zacc(acc);
    mm_lds<3>(acc, Hh, Hl, Wb, sE, sO);
    __syncthreads();                                       // done reading E2
    stage64k(Wb, ws + SWB + 1 * 32768, w, lane);
    bf16x8 Mh[2][4];
    {
        const short* mh = ws + MEANH;
        const size_t mr0 = (size_t)((r0w + lm) & (BATCH - 1)) * 128;
        const size_t mr1 = (size_t)((r0w + 16 + lm) & (BATCH - 1)) * 128;
        #pragma unroll
        for (int ks = 0; ks < 4; ++ks) {
            Mh[0][ks] = *(const bf16x8*)(mh + mr0 + 32 * ks + 8 * q);
            Mh[1][ks] = *(const bf16x8*)(mh + mr1 + 32 * ks + 8 * q);
        }
    }
    bf16x8 Eh[2][4], El[2][4];
    epi_state(acc, bf + 128, q * 4, Eh, El);               // eb2 -> E (lives long)
    __syncthreads();                                       // A1emb ready

    // ---- P2: L5 emb half (3-term)
    zacc(acc);
    mm_lds<3>(acc, Eh, El, Wb, sE, sO);
    __syncthreads();                                       // done reading A1emb
    stage64k(Wb, ws + SWB + 2 * 32768, w, lane);
    __syncthreads();                                       // A1mean ready

    // ---- P3: L5 mean half (2-term, accumulate); epi->A (hi only)
    mm_lds<2>(acc, Mh, Mh, Wb, sE, sO);
    __syncthreads();                                       // done reading A1mean
    stage64k(Wb, ws + SWB + 3 * 32768, w, lane);
    bf16x8 Ah[2][4];
    epi_state_hi(acc, bf + 4 * 128, q * 4, Ah);            // ab1 -> A
    __syncthreads();                                       // A2 ready

    // ---- P4: L6 (2-term); scores + softmax in-register (overlaps V1 staging)
    zacc(acc);
    mm_lds<2>(acc, Ah, Ah, Wb, sE, sO);
    __syncthreads();                                       // done reading A2
    stage64k(Wb, ws + SWB + 4 * 32768, w, lane);
    {
        const float* b6  = bf + 5 * 128;   // ab2
        const float* w3p = bf + 6 * 128;   // aW3 (ab3 cancels in softmax)
        float p0 = 0.f, p1 = 0.f;
        #pragma unroll
        for (int t = 0; t < 8; ++t) {
            float4 b  = ld4(b6 + 16 * t + 4 * q);
            float4 wv = ld4(w3p + 16 * t + 4 * q);
            p0 += tanh_f(acc[0][t][0] + b.x) * wv.x + tanh_f(acc[0][t][1] + b.y) * wv.y
                + tanh_f(acc[0][t][2] + b.z) * wv.z + tanh_f(acc[0][t][3] + b.w) * wv.w;
            p1 += tanh_f(acc[1][t][0] + b.x) * wv.x + tanh_f(acc[1][t][1] + b.y) * wv.y
                + tanh_f(acc[1][t][2] + b.z) * wv.z + tanh_f(acc[1][t][3] + b.w) * wv.w;
        }
        p0 += __shfl_xor(p0, 16); p0 += __shfl_xor(p0, 32);
        p1 += __shfl_xor(p1, 16); p1 += __shfl_xor(p1, 32);
        float m0 = p0, m1 = p1;
        m0 = fmaxf(m0, __shfl_xor(m0, 1)); m0 = fmaxf(m0, __shfl_xor(m0, 2)); m0 = fmaxf(m0, __shfl_xor(m0, 4));
        m1 = fmaxf(m1, __shfl_xor(m1, 1)); m1 = fmaxf(m1, __shfl_xor(m1, 2)); m1 = fmaxf(m1, __shfl_xor(m1, 4));
        float e0 = __expf(p0 - m0), e1 = __expf(p1 - m1);
        float s0 = e0, s1 = e1;
        s0 += __shfl_xor(s0, 1); s0 += __shfl_xor(s0, 2); s0 += __shfl_xor(s0, 4);
        s1 += __shfl_xor(s1, 1); s1 += __shfl_xor(s1, 2); s1 += __shfl_xor(s1, 4);
        a0 = e0 * __builtin_amdgcn_rcpf(s0);
        a1 = e1 * __builtin_amdgcn_rcpf(s1);
    }
    __syncthreads();                                       // V1 ready

    // ---- P5: L3 (3-term)
    zacc(acc);
    mm_lds<3>(acc, Eh, El, Wb, sE, sO);
    __syncthreads();                                       // done reading V1
    stage64k(Wb, ws + SWB + 5 * 32768, w, lane);
    bf16x8 Vh[2][4], Vl[2][4];
    epi_state(acc, bf + 2 * 128, q * 4, Vh, Vl);           // vb1 -> V
    __syncthreads();                                       // V2 ready

    // ---- P6: L4 (3-term); attn-weighted group sum -> out
    zacc(acc);
    mm_lds<3>(acc, Vh, Vl, Wb, sE, sO);
    const float* b4 = bf + 3 * 128;                        // vb2
    #pragma unroll
    for (int rt = 0; rt < 2; ++rt) {
        const float av = rt ? a1 : a0;
        float o[8][4];
        #pragma unroll
        for (int ks = 0; ks < 4; ++ks) {
            float4 b0 = ld4(b4 + 16 * ks + 4 * q);
            float4 b1 = ld4(b4 + 16 * ks + 64 + 4 * q);
            o[ks][0] = av * tanh_f(acc[rt][ks][0] + b0.x);
            o[ks][1] = av * tanh_f(acc[rt][ks][1] + b0.y);
            o[ks][2] = av * tanh_f(acc[rt][ks][2] + b0.z);
            o[ks][3] = av * tanh_f(acc[rt][ks][3] + b0.w);
            o[ks+4][0] = av * tanh_f(acc[rt][ks+4][0] + b1.x);
            o[ks+4][1] = av * tanh_f(acc[rt][ks+4][1] + b1.y);
            o[ks+4][2] = av * tanh_f(acc[rt][ks+4][2] + b1.z);
            o[ks+4][3] = av * tanh_f(acc[rt][ks+4][3] + b1.w);
        }
        #pragma unroll
        for (int t = 0; t < 8; ++t)
            #pragma unroll
            for (int e = 0; e < 4; ++e) {
                float v = o[t][e];
                v += __shfl_xor(v, 1); v += __shfl_xor(v, 2); v += __shfl_xor(v, 4);
                o[t][e] = v;
            }
        if ((lm & 7) == 0) {
            int g = (r0w >> 3) + 2 * rt + (lm >> 3);
            #pragma unroll
            for (int ks = 0; ks < 4; ++ks) {
                *(float4*)(out + (size_t)g * 128 + 32 * ks + 8 * q) =
                    make_float4(o[ks][0], o[ks][1], o[ks][2], o[ks][3]);
                *(float4*)(out + (size_t)g * 128 + 32 * ks + 8 * q + 4) =
                    make_float4(o[ks+4][0], o[ks+4][1], o[ks+4][2], o[ks+4][3]);
            }
        }
    }
}

extern "C" void kernel_launch(void* const* d_in, const int* in_sizes, int n_in,
                              void* d_out, int out_size, void* d_ws, size_t ws_size,
                              hipStream_t stream) {
    const float* self_obs = (const float*)d_in[0];
    const float* obs      = (const float*)d_in[1];
    const float* eW1 = (const float*)d_in[2];  const float* eb1 = (const float*)d_in[3];
    const float* eW2 = (const float*)d_in[4];  const float* eb2 = (const float*)d_in[5];
    const float* vW1 = (const float*)d_in[6];  const float* vb1 = (const float*)d_in[7];
    const float* vW2 = (const float*)d_in[8];  const float* vb2 = (const float*)d_in[9];
    const float* aW1 = (const float*)d_in[10]; const float* ab1 = (const float*)d_in[11];
    const float* aW2 = (const float*)d_in[12]; const float* ab2 = (const float*)d_in[13];
    const float* aW3 = (const float*)d_in[14];
    float* out = (float*)d_out;
    short* ws = (short*)d_ws;

    prep_w<<<404, 256, 0, stream>>>(eW1, eW2, vW1, vW2, aW1, aW2,
                                    eb1, eb2, vb1, vb2, ab1, ab2, aW3, ws);

    dim3 grid(4096);   // 4096 blocks x 4 waves x 32 rows = 524288 rows
    qk_mean<<<grid, NTHREADS, 0, stream>>>(self_obs, obs, ws);
    qk_main<<<grid, NTHREADS, 0, stream>>>(self_obs, obs, ws, out);
}